// Round 3
// baseline (503.765 us; speedup 1.0000x reference)
//
#include <hip/hip_runtime.h>
#include <hip/hip_bf16.h>

#define TT 4096
#define EE 512
#define AA 128

typedef short short8 __attribute__((ext_vector_type(8)));
typedef float f32x4 __attribute__((ext_vector_type(4)));

__device__ __forceinline__ short f2bf(float f) {
    union { float f; unsigned u; } v; v.f = f;
    unsigned r = v.u + 0x7fffu + ((v.u >> 16) & 1u);
    return (short)(r >> 16);
}

// ws layout (bytes)
#define WS_WVT   0           // bf16 [128][544]  : Wv^T cols 0..511, M^T cols 512..542, col 543 = 0
#define WS_QBIAS 139264      // f32 [32][128]    : query@Wq + bv + att_b
#define WS_NV    155648      // f32 [128]        : normalized att_v
#define WS_P     156160      // f32 [32][4096]   : sigmoid probabilities
#define WS_PART  680448      // f32 [32][8][512] : attn_c partials

// ---------------------------------------------------------------- fused prep
// blocks 0..271:  wvt[a][k] = Wv[k][a] (k<512) ; (conv_k@Wl)[k-512][a] (512<=k<543) ; 0 (k=543)
// blocks 272..303: q_bias[b][a] = query[b]@Wq[:,a] + bv[a] + att_b[a] ; block 272 also nv[a]
__global__ void prep_kernel(const float* __restrict__ Wv, const float* __restrict__ conv_k,
                            const float* __restrict__ Wl, const float* __restrict__ query,
                            const float* __restrict__ Wq, const float* __restrict__ bv,
                            const float* __restrict__ att_b, const float* __restrict__ att_v,
                            const float* __restrict__ att_g,
                            short* __restrict__ wvt, float* __restrict__ q_bias,
                            float* __restrict__ nv) {
    if (blockIdx.x < 272) {
        int idx = blockIdx.x * 256 + threadIdx.x;   // 0..69631  (128*544)
        int a = idx / 544, k = idx % 544;
        float val = 0.f;
        if (k < 512) {
            val = Wv[k * 128 + a];
        } else if (k < 543) {
            int kk = k - 512;
            float s = 0.f;
            #pragma unroll
            for (int c = 0; c < 32; ++c) s += conv_k[kk * 32 + c] * Wl[c * 128 + a];
            val = s;
        }
        wvt[a * 544 + k] = f2bf(val);
    } else {
        int b = blockIdx.x - 272, a = threadIdx.x;
        if (a < 128) {
            float s = 0.f;
            for (int d = 0; d < 512; ++d) s += query[b * 512 + d] * Wq[d * 128 + a];
            q_bias[b * 128 + a] = s + bv[a] + att_b[a];
            if (b == 0) {
                float ss = 0.f;
                #pragma unroll
                for (int i = 0; i < 128; ++i) { float t = att_v[i]; ss += t * t; }
                nv[a] = att_g[0] * att_v[a] * rsqrtf(ss);
            }
        }
    }
}

// ---------------------------------------------------------------- energy GEMM (no LDS, no barriers)
// rows = (b,t) 64/block, K = 512 (value@Wv) + 32 (location band), N = 128
// A-frag loaded straight from global (32 contiguous B/lane, coalesced);
// B-frag straight from L2-resident wvt panel. Epilogue: tanh, dot nv, sigmoid.
__global__ __launch_bounds__(256) void energy_kernel(
    const float* __restrict__ value, const int* __restrict__ vlen,
    const float* __restrict__ accum, const short* __restrict__ wvt,
    const float* __restrict__ q_bias, const float* __restrict__ nv,
    const float* __restrict__ score_bias, float* __restrict__ p_buf) {

    int bid = blockIdx.x;
    int b  = bid >> 6;             // 64 row-tiles per batch (T/64)
    int t0 = (bid & 63) << 6;
    int tid = threadIdx.x;
    int w = tid >> 6;              // wave: rows t0+w*16 .. +15
    int l = tid & 63;
    int l15 = l & 15, g = l >> 4;

    int len = vlen[b];
    if (t0 >= len) {               // fully-masked tile: p = 0, skip all work
        if (tid < 64) p_buf[b * TT + t0 + tid] = 0.f;
        return;
    }

    int row = t0 + w * 16 + l15;

    f32x4 acc[8];
    #pragma unroll
    for (int i = 0; i < 8; ++i) acc[i] = (f32x4){0.f, 0.f, 0.f, 0.f};

    const float* arow = value + ((size_t)(b * TT + row)) * EE + g * 8;
    const short* brow = wvt + l15 * 544 + g * 8;

    #pragma unroll 4
    for (int kc = 0; kc < 16; ++kc) {
        const float4* ap = (const float4*)(arow + kc * 32);
        float4 v0 = ap[0], v1 = ap[1];           // 32 contiguous bytes/lane
        short8 af;
        af[0] = f2bf(v0.x); af[1] = f2bf(v0.y); af[2] = f2bf(v0.z); af[3] = f2bf(v0.w);
        af[4] = f2bf(v1.x); af[5] = f2bf(v1.y); af[6] = f2bf(v1.z); af[7] = f2bf(v1.w);
        #pragma unroll
        for (int t8 = 0; t8 < 8; ++t8) {
            short8 bf = *(const short8*)(brow + t8 * 16 * 544 + kc * 32);
            acc[t8] = __builtin_amdgcn_mfma_f32_16x16x32_bf16(af, bf, acc[t8], 0, 0, 0);
        }
    }

    // band chunk (location conv as K-chunk 16): A[row][kk] = accum[b, row-15+kk]
    {
        short8 af;
        #pragma unroll
        for (int i = 0; i < 8; ++i) {
            int kk = g * 8 + i;
            int t = row - 15 + kk;
            float v = (kk < 31 && t >= 0 && t < TT) ? accum[b * TT + t] : 0.f;
            af[i] = f2bf(v);
        }
        #pragma unroll
        for (int t8 = 0; t8 < 8; ++t8) {
            short8 bf = *(const short8*)(brow + t8 * 16 * 544 + 512);
            acc[t8] = __builtin_amdgcn_mfma_f32_16x16x32_bf16(af, bf, acc[t8], 0, 0, 0);
        }
    }

    // --- epilogue: energy -> p   (C/D: col=lane&15 -> a-dim, row=(lane>>4)*4+j -> t-dim)
    float qb[8], nvv[8];
    #pragma unroll
    for (int t8 = 0; t8 < 8; ++t8) {
        int a = t8 * 16 + l15;
        qb[t8]  = q_bias[b * 128 + a];
        nvv[t8] = nv[a];
    }
    float sb = score_bias[0];
    #pragma unroll
    for (int j = 0; j < 4; ++j) {
        float e = 0.f;
        #pragma unroll
        for (int t8 = 0; t8 < 8; ++t8)
            e += tanhf(acc[t8][j] + qb[t8]) * nvv[t8];
        e += __shfl_xor(e, 1);
        e += __shfl_xor(e, 2);
        e += __shfl_xor(e, 4);
        e += __shfl_xor(e, 8);
        if (l15 == 0) {
            int t = t0 + w * 16 + g * 4 + j;
            float p = 0.f;
            if (t < len) { float ee = e + sb; p = 1.f / (1.f + expf(-ee)); }
            p_buf[b * TT + t] = p;
        }
    }
}

// ---------------------------------------------------------------- attn_weight (elementwise)
__global__ void weight_kernel(const float* __restrict__ p_buf, const float* __restrict__ prev,
                              float* __restrict__ outw) {
    int i = blockIdx.x * 256 + threadIdx.x;    // 0..131071
    int t = i & (TT - 1);
    float w = prev[i] * p_buf[i];
    if (t > 0) w += prev[i - 1] * (1.f - p_buf[i - 1]);
    outw[i] = w;
}

// ---------------------------------------------------------------- attn_c partials
__global__ __launch_bounds__(256) void ctx_partial(const float* __restrict__ value,
                                                   const float* __restrict__ wbuf,
                                                   float* __restrict__ part) {
    __shared__ float wsm[512];
    int b = blockIdx.x, tc = blockIdx.y;
    int tid = threadIdx.x;
    wsm[tid]       = wbuf[b * TT + tc * 512 + tid];
    wsm[tid + 256] = wbuf[b * TT + tc * 512 + tid + 256];
    __syncthreads();
    float ax = 0.f, ay = 0.f;
    const float* vbase = value + ((size_t)b * TT + tc * 512) * EE + tid * 2;
    for (int tt = 0; tt < 512; ++tt) {
        float wv = wsm[tt];
        if (wv != 0.f) {   // block-uniform skip: weights are near-one-hot sparse
            float2 v = *(const float2*)(vbase + (size_t)tt * EE);
            ax += wv * v.x; ay += wv * v.y;
        }
    }
    float2 r; r.x = ax; r.y = ay;
    *(float2*)(part + ((b * 8 + tc) * 512) + tid * 2) = r;
}

// ---------------------------------------------------------------- attn_c reduce
__global__ void ctx_reduce(const float* __restrict__ part, float* __restrict__ outc) {
    int idx = blockIdx.x * 256 + threadIdx.x;  // 0..16383
    int b = idx >> 9, e = idx & 511;
    float s = 0.f;
    #pragma unroll
    for (int tc = 0; tc < 8; ++tc) s += part[(b * 8 + tc) * 512 + e];
    outc[idx] = s;
}

// ---------------------------------------------------------------- launch
extern "C" void kernel_launch(void* const* d_in, const int* in_sizes, int n_in,
                              void* d_out, int out_size, void* d_ws, size_t ws_size,
                              hipStream_t stream) {
    const float* value  = (const float*)d_in[0];
    const int*   vlen   = (const int*)  d_in[1];
    const float* query  = (const float*)d_in[2];
    const float* accum  = (const float*)d_in[3];
    const float* prev   = (const float*)d_in[4];
    const float* Wv     = (const float*)d_in[5];
    const float* bv     = (const float*)d_in[6];
    const float* Wq     = (const float*)d_in[7];
    const float* conv_k = (const float*)d_in[8];
    const float* Wl     = (const float*)d_in[9];
    const float* att_v  = (const float*)d_in[10];
    const float* att_g  = (const float*)d_in[11];
    const float* att_b  = (const float*)d_in[12];
    const float* sbias  = (const float*)d_in[13];

    char* wsb = (char*)d_ws;
    short* wvt   = (short*)(wsb + WS_WVT);
    float* qbias = (float*)(wsb + WS_QBIAS);
    float* nv    = (float*)(wsb + WS_NV);
    float* pbuf  = (float*)(wsb + WS_P);
    float* part  = (float*)(wsb + WS_PART);

    float* outc = (float*)d_out;             // [32,512]
    float* outw = (float*)d_out + 32 * 512;  // [32,4096]

    prep_kernel<<<304, 256, 0, stream>>>(Wv, conv_k, Wl, query, Wq, bv, att_b,
                                         att_v, att_g, wvt, qbias, nv);
    energy_kernel<<<2048, 256, 0, stream>>>(value, vlen, accum, wvt, qbias, nv, sbias, pbuf);
    weight_kernel<<<512, 256, 0, stream>>>(pbuf, prev, outw);
    ctx_partial<<<dim3(32, 8), 256, 0, stream>>>(value, outw, part);
    ctx_reduce <<<64, 256, 0, stream>>>(part, outc);
}

// Round 5
// 424.351 us; speedup vs baseline: 1.1871x; 1.1871x over previous
//
#include <hip/hip_runtime.h>
#include <hip/hip_bf16.h>

#define TT 4096
#define EE 512
#define AA 128

typedef short short8 __attribute__((ext_vector_type(8)));
typedef float f32x4 __attribute__((ext_vector_type(4)));

__device__ __forceinline__ short f2bf(float f) {
    union { float f; unsigned u; } v; v.f = f;
    unsigned r = v.u + 0x7fffu + ((v.u >> 16) & 1u);
    return (short)(r >> 16);
}
__device__ __forceinline__ unsigned pk2bf(float lo, float hi) {
    // compiler emits v_cvt_pk_bf16_f32 (RNE) at -O3
    __hip_bfloat162 h = __float22bfloat162_rn(make_float2(lo, hi));
    union { __hip_bfloat162 h; unsigned u; } c; c.h = h;
    return c.u;
}

// ws layout (bytes)
#define WS_WVT   0           // bf16 [128][544]  : Wv^T cols 0..511, M^T cols 512..542, col 543=0
#define WS_QBIAS 139264      // f32 [32][128]    : query@Wq + bv + att_b
#define WS_NV    155648      // f32 [128]        : normalized att_v
#define WS_P     156160      // f32 [32][4096]   : sigmoid probabilities
#define WS_PART  680448      // f32 [32][8][512] : attn_c partials

// ---------------------------------------------------------------- prep
// blocks 0..271: wvt panel ; blocks 272..303: q_bias (+nv in block 272)
__global__ void prep_kernel(const float* __restrict__ Wv, const float* __restrict__ conv_k,
                            const float* __restrict__ Wl, const float* __restrict__ query,
                            const float* __restrict__ Wq, const float* __restrict__ bv,
                            const float* __restrict__ att_b, const float* __restrict__ att_v,
                            const float* __restrict__ att_g,
                            short* __restrict__ wvt, float* __restrict__ q_bias,
                            float* __restrict__ nv) {
    if (blockIdx.x < 272) {
        int idx = blockIdx.x * 256 + threadIdx.x;   // 0..69631  (128*544)
        int a = idx / 544, k = idx % 544;
        float val = 0.f;
        if (k < 512) {
            val = Wv[k * 128 + a];
        } else if (k < 543) {
            int kk = k - 512;
            float s = 0.f;
            #pragma unroll
            for (int c = 0; c < 32; ++c) s += conv_k[kk * 32 + c] * Wl[c * 128 + a];
            val = s;
        }
        wvt[a * 544 + k] = f2bf(val);
    } else {
        __shared__ float tmp[2][128];
        int b = blockIdx.x - 272;
        int a = threadIdx.x & 127, h = threadIdx.x >> 7;
        const float* q = query + b * 512 + h * 256;
        const float* wq = Wq + (h * 256) * 128 + a;
        float s = 0.f;
        #pragma unroll 4
        for (int d = 0; d < 256; ++d) s += q[d] * wq[d * 128];
        tmp[h][a] = s;
        __syncthreads();
        if (threadIdx.x < 128) {
            q_bias[b * 128 + a] = tmp[0][a] + tmp[1][a] + bv[a] + att_b[a];
            if (b == 0) {
                float ss = 0.f;
                #pragma unroll
                for (int i = 0; i < 128; ++i) { float t = att_v[i]; ss += t * t; }
                nv[a] = att_g[0] * att_v[a] * rsqrtf(ss);
            }
        }
    }
}

// ---------------------------------------------------------------- energy GEMM
// 128-row tile/block, 4 waves x (32 rows x 128 cols), K = 512 + 32 band.
// Reg-staged fp32->bf16 into double-buffered padded LDS; loads prefetched
// one chunk ahead (issued before the barrier) so HBM latency hides under MFMA.
__global__ __launch_bounds__(256, 3) void energy_kernel(
    const float* __restrict__ value, const int* __restrict__ vlen,
    const float* __restrict__ accum, const short* __restrict__ wvt,
    const float* __restrict__ q_bias, const float* __restrict__ nv,
    const float* __restrict__ score_bias, float* __restrict__ p_buf) {

    __shared__ __align__(16) short As[2][128 * 40];   // stride 40 shorts = 80B (bank spread)
    __shared__ __align__(16) short Bs[2][128 * 40];

    int bid = blockIdx.x;
    int b  = bid >> 5;             // 32 row-tiles per batch (T/128)
    int t0 = (bid & 31) << 7;
    int tid = threadIdx.x;
    int w = tid >> 6;              // wave: rows t0 + w*32 .. +31
    int l = tid & 63;
    int l15 = l & 15, g = l >> 4;

    int len = vlen[b];
    if (t0 >= len) {               // fully-masked tile
        if (tid < 128) p_buf[b * TT + t0 + tid] = 0.f;
        return;
    }

    // --- staging geometry (constant per thread)
    int arow[4], agrn[4];
    const float* abase[4];
    #pragma unroll
    for (int i = 0; i < 4; ++i) {
        int fl = tid + 256 * i;
        arow[i] = fl >> 3; agrn[i] = fl & 7;
        abase[i] = value + ((size_t)(b * TT + t0 + arow[i])) * EE + agrn[i] * 4;
    }
    int ba = tid >> 1, bh = (tid & 1) * 16;
    const short* bbase = wvt + ba * 544 + bh;

    f32x4 acc[2][8];
    #pragma unroll
    for (int rt = 0; rt < 2; ++rt)
        #pragma unroll
        for (int i = 0; i < 8; ++i) acc[rt][i] = (f32x4){0.f, 0.f, 0.f, 0.f};

    // --- prologue: load chunk 0
    float4 av[4];
    short8 bv0, bv1;
    #pragma unroll
    for (int i = 0; i < 4; ++i) av[i] = *(const float4*)(abase[i]);
    bv0 = *(const short8*)(bbase);
    bv1 = *(const short8*)(bbase + 8);

    int cur = 0;
    for (int kc = 0; kc < 16; ++kc) {
        // write staged regs -> LDS[cur]
        #pragma unroll
        for (int i = 0; i < 4; ++i) {
            uint2 pk;
            pk.x = pk2bf(av[i].x, av[i].y);
            pk.y = pk2bf(av[i].z, av[i].w);
            *(uint2*)(&As[cur][arow[i] * 40 + agrn[i] * 4]) = pk;
        }
        *(short8*)(&Bs[cur][ba * 40 + bh])     = bv0;
        *(short8*)(&Bs[cur][ba * 40 + bh + 8]) = bv1;

        // issue next-chunk loads (stay in flight across the barrier)
        if (kc < 15) {
            #pragma unroll
            for (int i = 0; i < 4; ++i) av[i] = *(const float4*)(abase[i] + (kc + 1) * 32);
            bv0 = *(const short8*)(bbase + (kc + 1) * 32);
            bv1 = *(const short8*)(bbase + (kc + 1) * 32 + 8);
        }
        __syncthreads();

        // compute chunk kc
        #pragma unroll
        for (int rt = 0; rt < 2; ++rt) {
            short8 af = *(const short8*)(&As[cur][(w * 32 + rt * 16 + l15) * 40 + g * 8]);
            #pragma unroll
            for (int t8 = 0; t8 < 8; ++t8) {
                short8 bf = *(const short8*)(&Bs[cur][(t8 * 16 + l15) * 40 + g * 8]);
                acc[rt][t8] = __builtin_amdgcn_mfma_f32_16x16x32_bf16(af, bf, acc[rt][t8], 0, 0, 0);
            }
        }
        cur ^= 1;
        __syncthreads();
    }

    // --- band chunk (location conv): register path, L2-hot B columns 512..543
    #pragma unroll
    for (int rt = 0; rt < 2; ++rt) {
        int row = t0 + w * 32 + rt * 16 + l15;
        short8 af;
        #pragma unroll
        for (int i = 0; i < 8; ++i) {
            int kk = g * 8 + i;
            int t = row - 15 + kk;
            float v = (kk < 31 && t >= 0 && t < TT) ? accum[b * TT + t] : 0.f;
            af[i] = f2bf(v);
        }
        #pragma unroll
        for (int t8 = 0; t8 < 8; ++t8) {
            short8 bf = *(const short8*)(wvt + (t8 * 16 + l15) * 544 + 512 + g * 8);
            acc[rt][t8] = __builtin_amdgcn_mfma_f32_16x16x32_bf16(af, bf, acc[rt][t8], 0, 0, 0);
        }
    }

    // --- epilogue: energy -> p   (C/D: col=lane&15 -> a, row=(lane>>4)*4+j -> t)
    float qb[8], nvv[8];
    #pragma unroll
    for (int t8 = 0; t8 < 8; ++t8) {
        int a = t8 * 16 + l15;
        qb[t8]  = q_bias[b * 128 + a];
        nvv[t8] = nv[a];
    }
    float sb = score_bias[0];
    #pragma unroll
    for (int rt = 0; rt < 2; ++rt) {
        #pragma unroll
        for (int j = 0; j < 4; ++j) {
            float e = 0.f;
            #pragma unroll
            for (int t8 = 0; t8 < 8; ++t8)
                e += tanhf(acc[rt][t8][j] + qb[t8]) * nvv[t8];
            e += __shfl_xor(e, 1);
            e += __shfl_xor(e, 2);
            e += __shfl_xor(e, 4);
            e += __shfl_xor(e, 8);
            if (l15 == 0) {
                int t = t0 + w * 32 + rt * 16 + g * 4 + j;
                float p = 0.f;
                if (t < len) { float ee = e + sb; p = 1.f / (1.f + expf(-ee)); }
                p_buf[b * TT + t] = p;
            }
        }
    }
}

// ---------------------------------------------------------------- fused weight + context partials
__global__ __launch_bounds__(256) void ctx_fused(const float* __restrict__ value,
                                                 const float* __restrict__ p_buf,
                                                 const float* __restrict__ prev,
                                                 float* __restrict__ outw,
                                                 float* __restrict__ part) {
    __shared__ float wsm[512];
    __shared__ int flags[8];
    int b = blockIdx.x, tc = blockIdx.y;
    int tid = threadIdx.x;
    if (tid < 8) flags[tid] = 0;
    __syncthreads();

    int tl = tid * 2;
    {
        int t = tc * 512 + tl;
        int gi = b * TT + t;
        float w0 = prev[gi] * p_buf[gi];
        if (t > 0) w0 += prev[gi - 1] * (1.f - p_buf[gi - 1]);
        float w1 = prev[gi + 1] * p_buf[gi + 1] + prev[gi] * (1.f - p_buf[gi]);
        outw[gi] = w0; outw[gi + 1] = w1;
        wsm[tl] = w0; wsm[tl + 1] = w1;
        if (w0 != 0.f) flags[tl >> 6] = 1;
        if (w1 != 0.f) flags[(tl + 1) >> 6] = 1;
    }
    __syncthreads();

    float ax = 0.f, ay = 0.f;
    const float* vbase = value + ((size_t)b * TT + tc * 512) * EE + tid * 2;
    for (int c = 0; c < 8; ++c) {
        if (flags[c]) {
            #pragma unroll 4
            for (int tt = c * 64; tt < c * 64 + 64; ++tt) {
                float wv = wsm[tt];
                if (wv != 0.f) {
                    float2 v = *(const float2*)(vbase + (size_t)tt * EE);
                    ax += wv * v.x; ay += wv * v.y;
                }
            }
        }
    }
    float2 r; r.x = ax; r.y = ay;
    *(float2*)(part + ((b * 8 + tc) * 512) + tid * 2) = r;
}

// ---------------------------------------------------------------- attn_c reduce
__global__ void ctx_reduce(const float* __restrict__ part, float* __restrict__ outc) {
    int idx = blockIdx.x * 256 + threadIdx.x;  // 0..16383
    int b = idx >> 9, e = idx & 511;
    float s = 0.f;
    #pragma unroll
    for (int tc = 0; tc < 8; ++tc) s += part[(b * 8 + tc) * 512 + e];
    outc[idx] = s;
}

// ---------------------------------------------------------------- launch
extern "C" void kernel_launch(void* const* d_in, const int* in_sizes, int n_in,
                              void* d_out, int out_size, void* d_ws, size_t ws_size,
                              hipStream_t stream) {
    const float* value  = (const float*)d_in[0];
    const int*   vlen   = (const int*)  d_in[1];
    const float* query  = (const float*)d_in[2];
    const float* accum  = (const float*)d_in[3];
    const float* prev   = (const float*)d_in[4];
    const float* Wv     = (const float*)d_in[5];
    const float* bv     = (const float*)d_in[6];
    const float* Wq     = (const float*)d_in[7];
    const float* conv_k = (const float*)d_in[8];
    const float* Wl     = (const float*)d_in[9];
    const float* att_v  = (const float*)d_in[10];
    const float* att_g  = (const float*)d_in[11];
    const float* att_b  = (const float*)d_in[12];
    const float* sbias  = (const float*)d_in[13];

    char* wsb = (char*)d_ws;
    short* wvt   = (short*)(wsb + WS_WVT);
    float* qbias = (float*)(wsb + WS_QBIAS);
    float* nv    = (float*)(wsb + WS_NV);
    float* pbuf  = (float*)(wsb + WS_P);
    float* part  = (float*)(wsb + WS_PART);

    float* outc = (float*)d_out;             // [32,512]
    float* outw = (float*)d_out + 32 * 512;  // [32,4096]

    prep_kernel<<<304, 256, 0, stream>>>(Wv, conv_k, Wl, query, Wq, bv, att_b,
                                         att_v, att_g, wvt, qbias, nv);
    energy_kernel<<<1024, 256, 0, stream>>>(value, vlen, accum, wvt, qbias, nv, sbias, pbuf);
    ctx_fused<<<dim3(32, 8), 256, 0, stream>>>(value, pbuf, prev, outw, part);
    ctx_reduce <<<64, 256, 0, stream>>>(part, outc);
}